// Round 4
// baseline (243.457 us; speedup 1.0000x reference)
//
#include <hip/hip_runtime.h>
#include <hip/hip_bf16.h>
#include <stdint.h>

// ---------------- types ----------------
typedef __attribute__((ext_vector_type(8))) short    bf16x8;
typedef __attribute__((ext_vector_type(4))) float    f32x4;
typedef __attribute__((ext_vector_type(8))) unsigned short u16x8;
typedef __attribute__((ext_vector_type(8))) _Float16 f16x8;

#define N_TOK   4096
#define C_DIM   768
#define NCLU    32

// RNE float->bf16
__device__ __forceinline__ uint16_t f2bf(float f){
  union { float f; unsigned u; } v; v.f = f;
  unsigned r = v.u + 0x7fffu + ((v.u >> 16) & 1u);
  return (uint16_t)(r >> 16);
}

__device__ __forceinline__ void gl2lds16(const void* g, void* l){
  __builtin_amdgcn_global_load_lds(
      (const __attribute__((address_space(1))) unsigned int*)g,
      (__attribute__((address_space(3))) unsigned int*)l, 16, 0, 0);
}

// ---------------- 2) per-cluster feature sums (no sort: wave-uniform scan of idx) ----------------
// grid (32 c, 3 ch-chunk, 4 j-chunk); csum must be zeroed first (memsetAsync).
__global__ __launch_bounds__(256) void csum_k(const float* __restrict__ x, const int* __restrict__ idx,
                                              float* __restrict__ csum){
  __shared__ int sidx[1024];
  const int c = blockIdx.x, chunk = blockIdx.y, jc = blockIdx.z;
  const int tid = threadIdx.x;
  #pragma unroll
  for (int u = 0; u < 4; ++u) sidx[u * 256 + tid] = idx[jc * 1024 + u * 256 + tid];
  __syncthreads();
  const int ch = chunk * 256 + tid;
  const int j0 = jc * 1024;
  float acc = 0.f;
  for (int j = 0; j < 1024; ++j)
    if (sidx[j] == c) acc += x[(size_t)(j0 + j) * C_DIM + ch];   // uniform branch: cheap skip
  atomicAdd(&csum[c * C_DIM + ch], acc);
}

// ---------------- 3) proxy (cluster_sum + distinct-cluster 8-neighbors), l2norm both -> bf16 ----------------
__global__ __launch_bounds__(256) void proxy_key_k(const float* __restrict__ x, const int* __restrict__ idx,
                                                   const float* __restrict__ csum,
                                                   uint16_t* __restrict__ An, uint16_t* __restrict__ Bn){
  __shared__ float red[8];
  const int i = blockIdx.x, tid = threadIdx.x;
  const int ci = idx[i];
  const int b = i >> 10, s = i & 1023, r = s >> 5, w = s & 31;
  const int drs[8] = {-1,-1,-1, 0, 0, 1, 1, 1};
  const int dws[8] = {-1, 0, 1,-1, 1,-1, 0, 1};
  int js[8]; unsigned mask = 0;
  #pragma unroll
  for (int t = 0; t < 8; ++t){
    int rr = r + drs[t], ww = w + dws[t];
    bool ok = ((unsigned)rr < 32u) && ((unsigned)ww < 32u);
    int j = (b << 10) + (rr << 5) + ww;
    js[t] = ok ? j : i;
    if (ok && idx[js[t]] != ci) mask |= (1u << t);
  }
  float xs[3], ps[3]; float ssx = 0.f, ssp = 0.f;
  #pragma unroll
  for (int u = 0; u < 3; ++u){
    int ch = tid + u * 256;
    float xv = x[(size_t)i * C_DIM + ch];
    float pv = csum[ci * C_DIM + ch];
    #pragma unroll
    for (int t = 0; t < 8; ++t)
      if (mask & (1u << t)) pv += x[(size_t)js[t] * C_DIM + ch];
    xs[u] = xv; ps[u] = pv;
    ssx += xv * xv; ssp += pv * pv;
  }
  for (int m = 32; m; m >>= 1){ ssx += __shfl_xor(ssx, m); ssp += __shfl_xor(ssp, m); }
  const int wid = tid >> 6;
  if ((tid & 63) == 0){ red[wid] = ssx; red[4 + wid] = ssp; }
  __syncthreads();
  ssx = red[0] + red[1] + red[2] + red[3];
  ssp = red[4] + red[5] + red[6] + red[7];
  float rnx = 1.f / fmaxf(sqrtf(ssx), 1e-12f);
  float rnp = 1.f / fmaxf(sqrtf(ssp), 1e-12f);
  #pragma unroll
  for (int u = 0; u < 3; ++u){
    int ch = tid + u * 256;
    Bn[(size_t)i * C_DIM + ch] = f2bf(xs[u] * rnx);
    An[(size_t)i * C_DIM + ch] = f2bf(ps[u] * rnp);
  }
}

// ---------------- 4/7) bf16 MFMA GEMM, C = A * B^T (A[M,K], B[N,K] row-major) ----------------
// 1D grid, XCD-aware swizzle (block g on XCD g%8).
// MODE 0: blocks [0,1024): 32m x 32n, K=768, fp16 S out.
//         blocks [1024,2560): fused bilinear resize 24x24->32x32 -> Vt (tail-fill).
// MODE 1: grid 768 = 32m x 6n x 4z (K-split), K=4096. fp16 stores of partial*rden[row]
//         into per-z buffers Obuf[z][4096][768] (no atomics).
template<int MODE>
__global__ __launch_bounds__(256) void gemm_bt_k(const uint16_t* __restrict__ A, const uint16_t* __restrict__ B,
                                                 int ldA, int ldB, int K,
                                                 _Float16* __restrict__ Sout,
                                                 const float* __restrict__ rden,
                                                 _Float16* __restrict__ Obuf,
                                                 const float* __restrict__ vext,
                                                 uint16_t* __restrict__ Vt){
  __shared__ __align__(16) char smem[32768];       // A tile 16KB @0, B tile 16KB @16384
  const int g = blockIdx.x;
  const int tid = threadIdx.x;

  if (MODE == 0 && g >= 1024){
    // ---- fused resize: block rb -> (bh, y) ----
    float* ld = (float*)smem;                      // 64 x 33 floats
    const int rb = g - 1024, bh = rb >> 5, y = rb & 31;
    const int b = bh / 12, h = bh % 12;
    const float* base = vext + (size_t)bh * 576 * 64;
    float sy = (y + 0.5f) * 0.75f - 0.5f;
    float fy0 = floorf(sy); float fy = sy - fy0; int y0 = (int)fy0;
    int iy0 = y0 < 0 ? 0 : y0;  int iy1 = (y0 + 1 > 23) ? 23 : y0 + 1;
    const int d = tid & 63, xg = tid >> 6;
    #pragma unroll
    for (int jj = 0; jj < 8; ++jj){
      int xx = xg + 4 * jj;
      float sx = (xx + 0.5f) * 0.75f - 0.5f;
      float fx0 = floorf(sx); float fx = sx - fx0; int x0 = (int)fx0;
      int ix0 = x0 < 0 ? 0 : x0;  int ix1 = (x0 + 1 > 23) ? 23 : x0 + 1;
      float v00 = base[(iy0 * 24 + ix0) * 64 + d];
      float v01 = base[(iy0 * 24 + ix1) * 64 + d];
      float v10 = base[(iy1 * 24 + ix0) * 64 + d];
      float v11 = base[(iy1 * 24 + ix1) * 64 + d];
      ld[d * 33 + xx] = (1.f - fy) * ((1.f - fx) * v00 + fx * v01)
                      +        fy  * ((1.f - fx) * v10 + fx * v11);
    }
    __syncthreads();
    const int xx = tid & 31, dg = tid >> 5;
    const int n = b * 1024 + y * 32 + xx;
    #pragma unroll
    for (int jj = 0; jj < 8; ++jj){
      int d2 = dg * 8 + jj;
      Vt[(size_t)(h * 64 + d2) * 4096 + n] = f2bf(ld[d2 * 33 + xx]);
    }
    return;
  }

  const int lane = tid & 63, wid = tid >> 6;
  const int q = lane >> 4, l16 = lane & 15;
  const int wrow = wid & 1, wcol = wid >> 1;

  // ---- XCD swizzle ----
  const int xcd = g & 7;
  const int j   = g >> 3;
  int i0, n0, kt0, per, z = 0;
  const int KT = K >> 6;
  if (MODE == 0){
    int sq = j >> 4;                                  // 0..7: 2x4 grid of 4x4 sub-blocks
    int mi = ((sq >> 2) << 2) + ((j >> 2) & 3);       // 0..7
    int ni = ((sq & 3) << 2) + (j & 3);               // 0..15
    i0 = (((xcd >> 1) << 3) + mi) * 128;              // m in [0,32)
    n0 = (((xcd & 1) << 4) + ni) * 128;               // n in [0,32)
    kt0 = 0; per = KT;
  } else {
    z  = xcd >> 1;                                    // 0..3
    i0 = (((xcd & 1) << 4) + j / 6) * 128;            // m in [0,32)
    n0 = (j % 6) * 128;                               // n in [0,6)
    per = KT >> 2; kt0 = z * per;
  }

  f32x4 acc[4][4] = {};

  for (int kt = kt0; kt < kt0 + per; ++kt){
    const int k0 = kt << 6;
    #pragma unroll
    for (int t = 0; t < 4; ++t){
      int p   = t * 256 + tid;
      int row = p >> 3, kc = p & 7;
      int kcs = kc ^ (row & 7);                    // XOR swizzle on the GLOBAL side
      gl2lds16(A + (size_t)(i0 + row) * ldA + k0 + kcs * 8, smem + p * 16);
      gl2lds16(B + (size_t)(n0 + row) * ldB + k0 + kcs * 8, smem + 16384 + p * 16);
    }
    __syncthreads();                               // drains vmcnt
    #pragma unroll
    for (int ks = 0; ks < 2; ++ks){
      bf16x8 af[4], bfr[4];
      #pragma unroll
      for (int mt = 0; mt < 4; ++mt){
        int row = wrow * 64 + mt * 16 + l16;
        int ck  = (ks * 4 + q) ^ (row & 7);
        af[mt] = *(const bf16x8*)(smem + row * 128 + ck * 16);
      }
      #pragma unroll
      for (int nt = 0; nt < 4; ++nt){
        int row = wcol * 64 + nt * 16 + l16;
        int ck  = (ks * 4 + q) ^ (row & 7);
        bfr[nt] = *(const bf16x8*)(smem + 16384 + row * 128 + ck * 16);
      }
      #pragma unroll
      for (int mt = 0; mt < 4; ++mt)
        #pragma unroll
        for (int nt = 0; nt < 4; ++nt)
          acc[mt][nt] = __builtin_amdgcn_mfma_f32_16x16x32_bf16(af[mt], bfr[nt], acc[mt][nt], 0, 0, 0);
    }
    __syncthreads();
  }

  _Float16* Pz = (MODE == 1) ? (Obuf + (size_t)z * N_TOK * C_DIM) : nullptr;
  #pragma unroll
  for (int mt = 0; mt < 4; ++mt){
    #pragma unroll
    for (int r = 0; r < 4; ++r){
      int row = i0 + wrow * 64 + mt * 16 + q * 4 + r;   // C/D: col=lane&15, row=(lane>>4)*4+reg
      float rd = (MODE == 1) ? rden[row] : 0.f;
      #pragma unroll
      for (int nt = 0; nt < 4; ++nt){
        int col = n0 + wcol * 64 + nt * 16 + l16;
        float v = acc[mt][nt][r];
        if (MODE == 0)
          Sout[(size_t)row * 4096 + col] = (_Float16)v;
        else
          Pz[(size_t)row * C_DIM + col] = (_Float16)(v * rd);
      }
    }
  }
}

// ---------------- 5/6) row stats + cut + exp -> P bf16, 1/denom ----------------
__global__ __launch_bounds__(256) void rowsoftmax_k(const _Float16* __restrict__ S, uint16_t* __restrict__ P,
                                                    float* __restrict__ rden){
  __shared__ float red[8];
  const int row = blockIdx.x, tid = threadIdx.x;
  const f16x8* Sr = (const f16x8*)(S + (size_t)row * 4096);
  f16x8 h0 = Sr[tid], h1 = Sr[256 + tid];
  float v[16];
  float mx = -3.4e38f, sm = 0.f;
  #pragma unroll
  for (int e = 0; e < 8; ++e){ v[e] = (float)h0[e]; v[8 + e] = (float)h1[e]; }
  #pragma unroll
  for (int e = 0; e < 16; ++e){ mx = fmaxf(mx, v[e]); sm += v[e]; }
  for (int m = 32; m; m >>= 1){ mx = fmaxf(mx, __shfl_xor(mx, m)); sm += __shfl_xor(sm, m); }
  const int wid = tid >> 6;
  if ((tid & 63) == 0){ red[wid] = mx; red[4 + wid] = sm; }
  __syncthreads();
  mx = fmaxf(fmaxf(red[0], red[1]), fmaxf(red[2], red[3]));
  sm = red[4] + red[5] + red[6] + red[7];

  float bmu  = 1.2f * fmaxf(sm * (1.f / 4096.f), 0.f);
  float amax = 3.0f * (mx - bmu);                 // identical expression to per-element 'a' below
  float cut  = fminf(amax, 0.1f);

  float den = 0.f; uint16_t pv[16];
  #pragma unroll
  for (int e = 0; e < 16; ++e){
    float a  = 3.0f * (v[e] - bmu);
    float ev = (a >= cut) ? __expf((a - amax) * (1.f / 0.07f)) : 0.f;
    den += ev;
    pv[e] = f2bf(ev);
  }
  for (int m = 32; m; m >>= 1) den += __shfl_xor(den, m);
  __syncthreads();
  if ((tid & 63) == 0) red[wid] = den;
  __syncthreads();
  den = red[0] + red[1] + red[2] + red[3];
  if (tid == 0) rden[row] = 1.f / den;            // den >= 1 (argmax always kept)

  u16x8* Pr = (u16x8*)(P + (size_t)row * 4096);
  u16x8 o0, o1;
  #pragma unroll
  for (int e = 0; e < 8; ++e){ o0[e] = pv[e]; o1[e] = pv[8 + e]; }
  Pr[tid] = o0; Pr[256 + tid] = o1;
}

// ---------------- 8) z-partial (fp16, pre-scaled) reduction + final layout ----------------
__global__ __launch_bounds__(256) void reduce_k(const _Float16* __restrict__ Pz, float* __restrict__ out){
  const int t = blockIdx.x * 256 + threadIdx.x;   // 8-col unit, 4096*96 total
  const int row = t / 96, c8 = t % 96;
  const size_t base = (size_t)row * C_DIM + c8 * 8;
  const size_t zs = (size_t)N_TOK * C_DIM;
  f16x8 a = *(const f16x8*)(Pz + base);
  f16x8 b = *(const f16x8*)(Pz + base + zs);
  f16x8 c = *(const f16x8*)(Pz + base + 2 * zs);
  f16x8 d = *(const f16x8*)(Pz + base + 3 * zs);
  float o[8];
  #pragma unroll
  for (int e = 0; e < 8; ++e)
    o[e] = (float)a[e] + (float)b[e] + (float)c[e] + (float)d[e];
  const int s = row & 1023, bb = row >> 10;       // out[s][b][c]
  float* dst = out + (size_t)s * 3072 + bb * 768 + c8 * 8;
  ((float4*)dst)[0] = make_float4(o[0], o[1], o[2], o[3]);
  ((float4*)dst)[1] = make_float4(o[4], o[5], o[6], o[7]);
}

// ---------------- launcher ----------------
extern "C" void kernel_launch(void* const* d_in, const int* in_sizes, int n_in,
                              void* d_out, int out_size, void* d_ws, size_t ws_size,
                              hipStream_t stream){
  (void)in_sizes; (void)n_in; (void)out_size; (void)ws_size;
  const float* ex   = (const float*)d_in[0];   // [4,1024,768] -> x[4096,768]
  const float* vext = (const float*)d_in[1];   // [48,24,24,64]
  const int*   idx  = (const int*)d_in[2];     // [4096]
  float* out = (float*)d_out;                  // [1024,4,768] fp32
  char* ws = (char*)d_ws;

  // ws layout (~90.3 MB). Region R is time-shared:
  //   phase A (gemm1/rowsoftmax): An(6.3M) | Bn(6.3M) | S16(33.5M)
  //   phase B (gemm2/reduce):     Pz fp16 partials 4 x 6.3M = 25.2M
  uint16_t* P    = (uint16_t*)(ws);                     // 33554432 B
  uint16_t* Vt   = (uint16_t*)(ws + 33554432);          //  6291456 B
  char*     R    = ws + 39845888;
  uint16_t* An   = (uint16_t*)(R);                      //  6291456 B
  uint16_t* Bn   = (uint16_t*)(R + 6291456);            //  6291456 B
  _Float16* S16  = (_Float16*)(R + 12582912);           // 33554432 B
  _Float16* Pz   = (_Float16*)(R);                      // 25165824 B (aliases An/Bn, phase B)
  float*    csum = (float*)(ws + 90177536);             //    98304 B
  float*    rden = (float*)(ws + 90275840);             //    16384 B

  hipMemsetAsync(csum, 0, NCLU * C_DIM * sizeof(float), stream);
  csum_k<<<dim3(NCLU, 3, 4), 256, 0, stream>>>(ex, idx, csum);
  proxy_key_k<<<N_TOK, 256, 0, stream>>>(ex, idx, csum, An, Bn);
  // S = proxyn @ keyn^T [4096x4096], K=768, fp16 out + fused resize tail (blocks >=1024)
  gemm_bt_k<0><<<2560, 256, 0, stream>>>(An, Bn, 768, 768, 768, S16, nullptr, nullptr, vext, Vt);
  rowsoftmax_k<<<N_TOK, 256, 0, stream>>>(S16, P, rden);
  // Pz[z] = (softmax(S) @ v) * rden   [4096 x 768], K=4096, K-split x4, fp16 stores
  gemm_bt_k<1><<<768, 256, 0, stream>>>(P, Vt, 4096, 4096, 4096, nullptr, rden, Pz, nullptr, nullptr);
  reduce_k<<<1536, 256, 0, stream>>>(Pz, out);
}

// Round 5
// 196.182 us; speedup vs baseline: 1.2410x; 1.2410x over previous
//
#include <hip/hip_runtime.h>
#include <hip/hip_bf16.h>
#include <stdint.h>

// ---------------- types ----------------
typedef __attribute__((ext_vector_type(8))) short    bf16x8;
typedef __attribute__((ext_vector_type(4))) float    f32x4;
typedef __attribute__((ext_vector_type(8))) unsigned short u16x8;
typedef __attribute__((ext_vector_type(8))) _Float16 f16x8;

#define N_TOK   4096
#define C_DIM   768
#define NCLU    32

// RNE float->bf16
__device__ __forceinline__ uint16_t f2bf(float f){
  union { float f; unsigned u; } v; v.f = f;
  unsigned r = v.u + 0x7fffu + ((v.u >> 16) & 1u);
  return (uint16_t)(r >> 16);
}

__device__ __forceinline__ void gl2lds16(const void* g, void* l){
  __builtin_amdgcn_global_load_lds(
      (const __attribute__((address_space(1))) unsigned int*)g,
      (__attribute__((address_space(3))) unsigned int*)l, 16, 0, 0);
}

// ---------------- 2a) per-cluster partial sums: scatter into LDS accumulator ----------------
// grid (128 token-chunks, 3 ch-chunks). Block: 32 tokens x 256 ch.
// LDS acc[32 clusters][256 ch] = 32 KB; DS RMW pipelined (no data-dependent branches).
// part[tc][c][ch] fp32, 12.6 MB.
__global__ __launch_bounds__(256) void csum_part_k(const float* __restrict__ x, const int* __restrict__ idx,
                                                   float* __restrict__ part){
  __shared__ float lacc[NCLU * 256];
  __shared__ int   sidx[32];
  const int tc = blockIdx.x, chunk = blockIdx.y;
  const int tid = threadIdx.x;
  #pragma unroll
  for (int u = 0; u < NCLU; ++u) lacc[u * 256 + tid] = 0.f;
  if (tid < 32) sidx[tid] = idx[tc * 32 + tid];
  __syncthreads();
  const int ch = chunk * 256 + tid;
  const float* xb = x + (size_t)(tc * 32) * C_DIM + ch;
  #pragma unroll 8
  for (int t = 0; t < 32; ++t){
    int c = sidx[t];                         // wave-uniform broadcast
    lacc[c * 256 + tid] += xb[(size_t)t * C_DIM];
  }
  __syncthreads();
  float* pb = part + ((size_t)tc * NCLU) * C_DIM + chunk * 256 + tid;
  #pragma unroll
  for (int c = 0; c < NCLU; ++c) pb[(size_t)c * C_DIM] = lacc[c * 256 + tid];
}

// ---------------- 2b) reduce partials -> csum[32][768] ----------------
__global__ __launch_bounds__(256) void csum_red_k(const float* __restrict__ part, float* __restrict__ csum){
  const int t = blockIdx.x * 256 + threadIdx.x;   // [0, 24576)
  float acc = 0.f;
  #pragma unroll 8
  for (int tc = 0; tc < 128; ++tc) acc += part[(size_t)tc * (NCLU * C_DIM) + t];
  csum[t] = acc;
}

// ---------------- 3) proxy (cluster_sum + distinct-cluster 8-neighbors), l2norm both -> bf16 ----------------
__global__ __launch_bounds__(256) void proxy_key_k(const float* __restrict__ x, const int* __restrict__ idx,
                                                   const float* __restrict__ csum,
                                                   uint16_t* __restrict__ An, uint16_t* __restrict__ Bn){
  __shared__ float red[8];
  const int i = blockIdx.x, tid = threadIdx.x;
  const int ci = idx[i];
  const int b = i >> 10, s = i & 1023, r = s >> 5, w = s & 31;
  const int drs[8] = {-1,-1,-1, 0, 0, 1, 1, 1};
  const int dws[8] = {-1, 0, 1,-1, 1,-1, 0, 1};
  int js[8]; unsigned mask = 0;
  #pragma unroll
  for (int t = 0; t < 8; ++t){
    int rr = r + drs[t], ww = w + dws[t];
    bool ok = ((unsigned)rr < 32u) && ((unsigned)ww < 32u);
    int j = (b << 10) + (rr << 5) + ww;
    js[t] = ok ? j : i;
    if (ok && idx[js[t]] != ci) mask |= (1u << t);
  }
  float xs[3], ps[3]; float ssx = 0.f, ssp = 0.f;
  #pragma unroll
  for (int u = 0; u < 3; ++u){
    int ch = tid + u * 256;
    float xv = x[(size_t)i * C_DIM + ch];
    float pv = csum[ci * C_DIM + ch];
    #pragma unroll
    for (int t = 0; t < 8; ++t)
      if (mask & (1u << t)) pv += x[(size_t)js[t] * C_DIM + ch];
    xs[u] = xv; ps[u] = pv;
    ssx += xv * xv; ssp += pv * pv;
  }
  for (int m = 32; m; m >>= 1){ ssx += __shfl_xor(ssx, m); ssp += __shfl_xor(ssp, m); }
  const int wid = tid >> 6;
  if ((tid & 63) == 0){ red[wid] = ssx; red[4 + wid] = ssp; }
  __syncthreads();
  ssx = red[0] + red[1] + red[2] + red[3];
  ssp = red[4] + red[5] + red[6] + red[7];
  float rnx = 1.f / fmaxf(sqrtf(ssx), 1e-12f);
  float rnp = 1.f / fmaxf(sqrtf(ssp), 1e-12f);
  #pragma unroll
  for (int u = 0; u < 3; ++u){
    int ch = tid + u * 256;
    Bn[(size_t)i * C_DIM + ch] = f2bf(xs[u] * rnx);
    An[(size_t)i * C_DIM + ch] = f2bf(ps[u] * rnp);
  }
}

// ---------------- 4/7) bf16 MFMA GEMM, C = A * B^T (A[M,K], B[N,K] row-major) ----------------
// 1D grid, XCD-aware swizzle (block g on XCD g%8).
// MODE 0: blocks [0,1024): 32m x 32n, K=768, fp16 S out.
//         blocks [1024,2560): fused bilinear resize 24x24->32x32 -> Vt (tail-fill).
// MODE 1: grid 768 = 32m x 6n x 4z (K-split), K=4096. fp16 stores of partial*rden[row]
//         into per-z buffers Obuf[z][4096][768] (no atomics).
template<int MODE>
__global__ __launch_bounds__(256) void gemm_bt_k(const uint16_t* __restrict__ A, const uint16_t* __restrict__ B,
                                                 int ldA, int ldB, int K,
                                                 _Float16* __restrict__ Sout,
                                                 const float* __restrict__ rden,
                                                 _Float16* __restrict__ Obuf,
                                                 const float* __restrict__ vext,
                                                 uint16_t* __restrict__ Vt){
  __shared__ __align__(16) char smem[32768];       // A tile 16KB @0, B tile 16KB @16384
  const int g = blockIdx.x;
  const int tid = threadIdx.x;

  if (MODE == 0 && g >= 1024){
    // ---- fused resize: block rb -> (bh, y) ----
    float* ld = (float*)smem;                      // 64 x 33 floats
    const int rb = g - 1024, bh = rb >> 5, y = rb & 31;
    const int b = bh / 12, h = bh % 12;
    const float* base = vext + (size_t)bh * 576 * 64;
    float sy = (y + 0.5f) * 0.75f - 0.5f;
    float fy0 = floorf(sy); float fy = sy - fy0; int y0 = (int)fy0;
    int iy0 = y0 < 0 ? 0 : y0;  int iy1 = (y0 + 1 > 23) ? 23 : y0 + 1;
    const int d = tid & 63, xg = tid >> 6;
    #pragma unroll
    for (int jj = 0; jj < 8; ++jj){
      int xx = xg + 4 * jj;
      float sx = (xx + 0.5f) * 0.75f - 0.5f;
      float fx0 = floorf(sx); float fx = sx - fx0; int x0 = (int)fx0;
      int ix0 = x0 < 0 ? 0 : x0;  int ix1 = (x0 + 1 > 23) ? 23 : x0 + 1;
      float v00 = base[(iy0 * 24 + ix0) * 64 + d];
      float v01 = base[(iy0 * 24 + ix1) * 64 + d];
      float v10 = base[(iy1 * 24 + ix0) * 64 + d];
      float v11 = base[(iy1 * 24 + ix1) * 64 + d];
      ld[d * 33 + xx] = (1.f - fy) * ((1.f - fx) * v00 + fx * v01)
                      +        fy  * ((1.f - fx) * v10 + fx * v11);
    }
    __syncthreads();
    const int xx = tid & 31, dg = tid >> 5;
    const int n = b * 1024 + y * 32 + xx;
    #pragma unroll
    for (int jj = 0; jj < 8; ++jj){
      int d2 = dg * 8 + jj;
      Vt[(size_t)(h * 64 + d2) * 4096 + n] = f2bf(ld[d2 * 33 + xx]);
    }
    return;
  }

  const int lane = tid & 63, wid = tid >> 6;
  const int q = lane >> 4, l16 = lane & 15;
  const int wrow = wid & 1, wcol = wid >> 1;

  // ---- XCD swizzle ----
  const int xcd = g & 7;
  const int j   = g >> 3;
  int i0, n0, kt0, per, z = 0;
  const int KT = K >> 6;
  if (MODE == 0){
    int sq = j >> 4;                                  // 0..7: 2x4 grid of 4x4 sub-blocks
    int mi = ((sq >> 2) << 2) + ((j >> 2) & 3);       // 0..7
    int ni = ((sq & 3) << 2) + (j & 3);               // 0..15
    i0 = (((xcd >> 1) << 3) + mi) * 128;              // m in [0,32)
    n0 = (((xcd & 1) << 4) + ni) * 128;               // n in [0,32)
    kt0 = 0; per = KT;
  } else {
    z  = xcd >> 1;                                    // 0..3
    i0 = (((xcd & 1) << 4) + j / 6) * 128;            // m in [0,32)
    n0 = (j % 6) * 128;                               // n in [0,6)
    per = KT >> 2; kt0 = z * per;
  }

  f32x4 acc[4][4] = {};

  for (int kt = kt0; kt < kt0 + per; ++kt){
    const int k0 = kt << 6;
    #pragma unroll
    for (int t = 0; t < 4; ++t){
      int p   = t * 256 + tid;
      int row = p >> 3, kc = p & 7;
      int kcs = kc ^ (row & 7);                    // XOR swizzle on the GLOBAL side
      gl2lds16(A + (size_t)(i0 + row) * ldA + k0 + kcs * 8, smem + p * 16);
      gl2lds16(B + (size_t)(n0 + row) * ldB + k0 + kcs * 8, smem + 16384 + p * 16);
    }
    __syncthreads();                               // drains vmcnt
    #pragma unroll
    for (int ks = 0; ks < 2; ++ks){
      bf16x8 af[4], bfr[4];
      #pragma unroll
      for (int mt = 0; mt < 4; ++mt){
        int row = wrow * 64 + mt * 16 + l16;
        int ck  = (ks * 4 + q) ^ (row & 7);
        af[mt] = *(const bf16x8*)(smem + row * 128 + ck * 16);
      }
      #pragma unroll
      for (int nt = 0; nt < 4; ++nt){
        int row = wcol * 64 + nt * 16 + l16;
        int ck  = (ks * 4 + q) ^ (row & 7);
        bfr[nt] = *(const bf16x8*)(smem + 16384 + row * 128 + ck * 16);
      }
      #pragma unroll
      for (int mt = 0; mt < 4; ++mt)
        #pragma unroll
        for (int nt = 0; nt < 4; ++nt)
          acc[mt][nt] = __builtin_amdgcn_mfma_f32_16x16x32_bf16(af[mt], bfr[nt], acc[mt][nt], 0, 0, 0);
    }
    __syncthreads();
  }

  _Float16* Pz = (MODE == 1) ? (Obuf + (size_t)z * N_TOK * C_DIM) : nullptr;
  #pragma unroll
  for (int mt = 0; mt < 4; ++mt){
    #pragma unroll
    for (int r = 0; r < 4; ++r){
      int row = i0 + wrow * 64 + mt * 16 + q * 4 + r;   // C/D: col=lane&15, row=(lane>>4)*4+reg
      float rd = (MODE == 1) ? rden[row] : 0.f;
      #pragma unroll
      for (int nt = 0; nt < 4; ++nt){
        int col = n0 + wcol * 64 + nt * 16 + l16;
        float v = acc[mt][nt][r];
        if (MODE == 0)
          Sout[(size_t)row * 4096 + col] = (_Float16)v;
        else
          Pz[(size_t)row * C_DIM + col] = (_Float16)(v * rd);
      }
    }
  }
}

// ---------------- 5/6) row stats + cut + exp -> P bf16, 1/denom ----------------
__global__ __launch_bounds__(256) void rowsoftmax_k(const _Float16* __restrict__ S, uint16_t* __restrict__ P,
                                                    float* __restrict__ rden){
  __shared__ float red[8];
  const int row = blockIdx.x, tid = threadIdx.x;
  const f16x8* Sr = (const f16x8*)(S + (size_t)row * 4096);
  f16x8 h0 = Sr[tid], h1 = Sr[256 + tid];
  float v[16];
  float mx = -3.4e38f, sm = 0.f;
  #pragma unroll
  for (int e = 0; e < 8; ++e){ v[e] = (float)h0[e]; v[8 + e] = (float)h1[e]; }
  #pragma unroll
  for (int e = 0; e < 16; ++e){ mx = fmaxf(mx, v[e]); sm += v[e]; }
  for (int m = 32; m; m >>= 1){ mx = fmaxf(mx, __shfl_xor(mx, m)); sm += __shfl_xor(sm, m); }
  const int wid = tid >> 6;
  if ((tid & 63) == 0){ red[wid] = mx; red[4 + wid] = sm; }
  __syncthreads();
  mx = fmaxf(fmaxf(red[0], red[1]), fmaxf(red[2], red[3]));
  sm = red[4] + red[5] + red[6] + red[7];

  float bmu  = 1.2f * fmaxf(sm * (1.f / 4096.f), 0.f);
  float amax = 3.0f * (mx - bmu);                 // identical expression to per-element 'a' below
  float cut  = fminf(amax, 0.1f);

  float den = 0.f; uint16_t pv[16];
  #pragma unroll
  for (int e = 0; e < 16; ++e){
    float a  = 3.0f * (v[e] - bmu);
    float ev = (a >= cut) ? __expf((a - amax) * (1.f / 0.07f)) : 0.f;
    den += ev;
    pv[e] = f2bf(ev);
  }
  for (int m = 32; m; m >>= 1) den += __shfl_xor(den, m);
  __syncthreads();
  if ((tid & 63) == 0) red[wid] = den;
  __syncthreads();
  den = red[0] + red[1] + red[2] + red[3];
  if (tid == 0) rden[row] = 1.f / den;            // den >= 1 (argmax always kept)

  u16x8* Pr = (u16x8*)(P + (size_t)row * 4096);
  u16x8 o0, o1;
  #pragma unroll
  for (int e = 0; e < 8; ++e){ o0[e] = pv[e]; o1[e] = pv[8 + e]; }
  Pr[tid] = o0; Pr[256 + tid] = o1;
}

// ---------------- 8) z-partial (fp16, pre-scaled) reduction + final layout ----------------
__global__ __launch_bounds__(256) void reduce_k(const _Float16* __restrict__ Pz, float* __restrict__ out){
  const int t = blockIdx.x * 256 + threadIdx.x;   // 8-col unit, 4096*96 total
  const int row = t / 96, c8 = t % 96;
  const size_t base = (size_t)row * C_DIM + c8 * 8;
  const size_t zs = (size_t)N_TOK * C_DIM;
  f16x8 a = *(const f16x8*)(Pz + base);
  f16x8 b = *(const f16x8*)(Pz + base + zs);
  f16x8 c = *(const f16x8*)(Pz + base + 2 * zs);
  f16x8 d = *(const f16x8*)(Pz + base + 3 * zs);
  float o[8];
  #pragma unroll
  for (int e = 0; e < 8; ++e)
    o[e] = (float)a[e] + (float)b[e] + (float)c[e] + (float)d[e];
  const int s = row & 1023, bb = row >> 10;       // out[s][b][c]
  float* dst = out + (size_t)s * 3072 + bb * 768 + c8 * 8;
  ((float4*)dst)[0] = make_float4(o[0], o[1], o[2], o[3]);
  ((float4*)dst)[1] = make_float4(o[4], o[5], o[6], o[7]);
}

// ---------------- launcher ----------------
extern "C" void kernel_launch(void* const* d_in, const int* in_sizes, int n_in,
                              void* d_out, int out_size, void* d_ws, size_t ws_size,
                              hipStream_t stream){
  (void)in_sizes; (void)n_in; (void)out_size; (void)ws_size;
  const float* ex   = (const float*)d_in[0];   // [4,1024,768] -> x[4096,768]
  const float* vext = (const float*)d_in[1];   // [48,24,24,64]
  const int*   idx  = (const int*)d_in[2];     // [4096]
  float* out = (float*)d_out;                  // [1024,4,768] fp32
  char* ws = (char*)d_ws;

  // ws layout (~90.3 MB). Time-shared regions:
  //   pre-phase: csum partials (12.6M) live in the P region (free until rowsoftmax)
  //   phase A (gemm1/rowsoftmax): An | Bn | S16 in R
  //   phase B (gemm2/reduce):     Pz fp16 partials 4 x 6.3M = 25.2M in R
  uint16_t* P    = (uint16_t*)(ws);                     // 33554432 B
  float*    part = (float*)(ws);                        // 12582912 B (aliases P, pre-phase)
  uint16_t* Vt   = (uint16_t*)(ws + 33554432);          //  6291456 B
  char*     R    = ws + 39845888;
  uint16_t* An   = (uint16_t*)(R);                      //  6291456 B
  uint16_t* Bn   = (uint16_t*)(R + 6291456);            //  6291456 B
  _Float16* S16  = (_Float16*)(R + 12582912);           // 33554432 B
  _Float16* Pz   = (_Float16*)(R);                      // 25165824 B (aliases An/Bn, phase B)
  float*    csum = (float*)(ws + 90177536);             //    98304 B
  float*    rden = (float*)(ws + 90275840);             //    16384 B

  csum_part_k<<<dim3(128, 3), 256, 0, stream>>>(ex, idx, part);
  csum_red_k<<<96, 256, 0, stream>>>(part, csum);
  proxy_key_k<<<N_TOK, 256, 0, stream>>>(ex, idx, csum, An, Bn);
  // S = proxyn @ keyn^T [4096x4096], K=768, fp16 out + fused resize tail (blocks >=1024)
  gemm_bt_k<0><<<2560, 256, 0, stream>>>(An, Bn, 768, 768, 768, S16, nullptr, nullptr, vext, Vt);
  rowsoftmax_k<<<N_TOK, 256, 0, stream>>>(S16, P, rden);
  // Pz[z] = (softmax(S) @ v) * rden   [4096 x 768], K=4096, K-split x4, fp16 stores
  gemm_bt_k<1><<<768, 256, 0, stream>>>(P, Vt, 4096, 4096, 4096, nullptr, rden, Pz, nullptr, nullptr);
  reduce_k<<<1536, 256, 0, stream>>>(Pz, out);
}